// Round 7
// baseline (135.191 us; speedup 1.0000x reference)
//
#include <hip/hip_runtime.h>
#include <math.h>

// Problem constants
#define BB    16
#define TT    2048
#define VOCAB 14
#define TOKD  8
#define POSD  8
#define DM    16      // TOKD + POSD
#define NH    2
#define HD    3
#define AD    6       // NH*HD
#define FFND  3

#define NTOK  (BB*TT)            // 32768
#define BH    (BB*NH)            // 32
// Grid = 1024 blocks exactly (4 blocks/CU co-resident, no dispatch tail):
//   bid <  896: full tiles (c < s), 28 per bh
//   bid >= 896: merged diagonal pairs: (s=2m,c=2m)+(s=2m+1,c=2m+1), 4 per bh
#define NFULL 896
#define NGRID 1024

struct P {
    const int*   idx;
    const float* tok_emb;
    const float* pos_enc;
    const float* Wq;
    const float* Wk;
    const float* Wv;
    const float* Wo;
    const float* ln1w;
    const float* ln1b;
    const float* ln2w;
    const float* ln2b;
    const float* lnfw;
    const float* lnfb;
    const float* W1;
    const float* b1;
    const float* W2;
    const float* b2;
    const float* Wh;
    float*       out;
    float4*      pbuf;   // [BH][8][TT] chunk partials {a0,a1,a2,l}, transposed
};

// LN1 output for token (b, t): embeddings gather + layernorm.
__device__ __forceinline__ void ln1_of(const P& p, int b, int t, float* h) {
    float x[DM];
    int tok = p.idx[b * TT + t];
    #pragma unroll
    for (int j = 0; j < TOKD; ++j) x[j]        = p.tok_emb[tok * TOKD + j];
    #pragma unroll
    for (int j = 0; j < POSD; ++j) x[TOKD + j] = p.pos_enc[t * POSD + j];

    float m = 0.f;
    #pragma unroll
    for (int j = 0; j < DM; ++j) m += x[j];
    m *= (1.f / DM);
    float v = 0.f;
    #pragma unroll
    for (int j = 0; j < DM; ++j) { float d = x[j] - m; v += d * d; }
    v *= (1.f / DM);
    float rs = rsqrtf(v + 1e-5f);
    #pragma unroll
    for (int j = 0; j < DM; ++j)
        h[j] = (x[j] - m) * rs * p.ln1w[j] + p.ln1b[j];
}

#define LOADKV(it)                                                             \
    float4 Kr = skv[((kw + (it)) << 1)];                                       \
    float4 Vr = skv[((kw + (it)) << 1) + 1];                                   \
    float k0 = Kr.x, k1 = Kr.y, k2 = Kr.z;                                     \
    float v0 = Vr.x, v1 = Vr.y, v2 = Vr.z;

// ---------------------------------------------------------------------------
// One 256x256 attention tile (the proven R6 body, verbatim): inline prep of
// K/V (key-tokens) and prescaled Q (query-tokens) for this block's head into
// LDS, 64-key broadcast inner loop per wave, 4-wave LDS reduce, transposed
// pbuf store. Safe to call twice per block: call-2's post-prologue sync
// orders all of call-1's spart reads before call-2's spart writes.
// ---------------------------------------------------------------------------
__device__ __forceinline__ void tile_work(const P& p, float4* skv, float4* sq,
                                          float4* spart, int tid,
                                          int bh, int s, int c) {
    int b  = bh >> 1;               // NH = 2
    int hh = bh & 1;

    // --- inline prep: key-token for K/V, query-token for Q (this head only)
    {
        float hK[DM];
        ln1_of(p, b, (c << 8) + tid, hK);
        float k0=0.f,k1=0.f,k2=0.f,v0=0.f,v1=0.f,v2=0.f;
        const float* wk  = p.Wk + (hh * 3) * 8;
        const float* wv_ = p.Wv + (hh * 3) * 8;
        #pragma unroll
        for (int j = 0; j < 8; ++j) {
            k0 = fmaf(wk[j],      hK[TOKD + j], k0);
            k1 = fmaf(wk[8 + j],  hK[TOKD + j], k1);
            k2 = fmaf(wk[16 + j], hK[TOKD + j], k2);
            v0 = fmaf(wv_[j],      hK[j], v0);
            v1 = fmaf(wv_[8 + j],  hK[j], v1);
            v2 = fmaf(wv_[16 + j], hK[j], v2);
        }
        skv[(tid << 1)]     = make_float4(k0, k1, k2, 0.f);
        skv[(tid << 1) + 1] = make_float4(v0, v1, v2, 0.f);

        float hQ[DM];
        if (c != s) {
            ln1_of(p, b, (s << 8) + tid, hQ);
        } else {
            #pragma unroll
            for (int j = 0; j < DM; ++j) hQ[j] = hK[j];   // same tokens
        }
        const float QS = 1.4426950408889634f / 1.7320508075688772f; // log2e/sqrt(HD)
        float q0=0.f,q1=0.f,q2=0.f;
        const float* wq = p.Wq + (hh * 3) * 8;
        #pragma unroll
        for (int j = 0; j < 8; ++j) {
            q0 = fmaf(wq[j],      hQ[TOKD + j], q0);
            q1 = fmaf(wq[8 + j],  hQ[TOKD + j], q1);
            q2 = fmaf(wq[16 + j], hQ[TOKD + j], q2);
        }
        sq[tid] = make_float4(q0 * QS, q1 * QS, q2 * QS, 0.f);
    }
    __syncthreads();

    int wv   = tid >> 6;
    int lane = tid & 63;
    int kw   = wv << 6;

    float4 qr[4];
    #pragma unroll
    for (int j = 0; j < 4; ++j) qr[j] = sq[(j << 6) + lane];

    float ac[4][4];
    #pragma unroll
    for (int j = 0; j < 4; ++j)
        ac[j][0] = ac[j][1] = ac[j][2] = ac[j][3] = 0.f;

    if (c < s) {
        // fully unmasked: one K/V read serves all 4 query groups
        #pragma unroll 4
        for (int it = 0; it < 64; ++it) {
            LOADKV(it)
            #pragma unroll
            for (int j = 0; j < 4; ++j) {
                float sc = fmaf(qr[j].x, k0, fmaf(qr[j].y, k1, qr[j].z * k2));
                float pr = __builtin_amdgcn_exp2f(sc);
                ac[j][0] = fmaf(pr, v0, ac[j][0]);
                ac[j][1] = fmaf(pr, v1, ac[j][1]);
                ac[j][2] = fmaf(pr, v2, ac[j][2]);
                ac[j][3] += pr;
            }
        }
    } else {
        // diagonal tile: wave wv sees keys 64wv..64wv+63.
        // group j<wv fully masked (skip); j==wv triangular; j>wv unmasked.
        #pragma unroll
        for (int j = 0; j < 4; ++j) {
            if (j < wv) continue;              // wave-uniform skip
            if (j == wv) {
                #pragma unroll 4
                for (int it = 0; it < 64; ++it) {
                    LOADKV(it)
                    float sc = fmaf(qr[j].x, k0, fmaf(qr[j].y, k1, qr[j].z * k2));
                    float pr = __builtin_amdgcn_exp2f(sc);
                    pr = (it <= lane) ? pr : 0.f;
                    ac[j][0] = fmaf(pr, v0, ac[j][0]);
                    ac[j][1] = fmaf(pr, v1, ac[j][1]);
                    ac[j][2] = fmaf(pr, v2, ac[j][2]);
                    ac[j][3] += pr;
                }
            } else {
                #pragma unroll 4
                for (int it = 0; it < 64; ++it) {
                    LOADKV(it)
                    float sc = fmaf(qr[j].x, k0, fmaf(qr[j].y, k1, qr[j].z * k2));
                    float pr = __builtin_amdgcn_exp2f(sc);
                    ac[j][0] = fmaf(pr, v0, ac[j][0]);
                    ac[j][1] = fmaf(pr, v1, ac[j][1]);
                    ac[j][2] = fmaf(pr, v2, ac[j][2]);
                    ac[j][3] += pr;
                }
            }
        }
    }

    // per-wave partials (16B lane stride: 2-way, free)
    #pragma unroll
    for (int j = 0; j < 4; ++j)
        spart[(wv << 8) + (j << 6) + lane] =
            make_float4(ac[j][0], ac[j][1], ac[j][2], ac[j][3]);
    __syncthreads();

    // block reduce across 4 waves; coalesced transposed pbuf store
    float4 p0 = spart[tid];
    float4 p1 = spart[256 + tid];
    float4 p2 = spart[512 + tid];
    float4 p3 = spart[768 + tid];
    float4 acc = make_float4(p0.x+p1.x+p2.x+p3.x, p0.y+p1.y+p2.y+p3.y,
                             p0.z+p1.z+p2.z+p3.z, p0.w+p1.w+p2.w+p3.w);
    p.pbuf[((size_t)bh * 8 + c) * TT + (s << 8) + tid] = acc;
}

// ---------------------------------------------------------------------------
// Kernel 1: attention, 1024-block grid (no dispatch tail at 4 blocks/CU).
// ---------------------------------------------------------------------------
__global__ __launch_bounds__(256, 4) void attn_kernel(P p) {
    __shared__ float4 skv[512];      // 8 KB
    __shared__ float4 sq[256];       // 4 KB
    __shared__ float4 spart[1024];   // 16 KB

    const int tid = threadIdx.x;
    int bid = blockIdx.x;

    if (bid < NFULL) {
        // full tiles (c < s): 28 per bh
        int bh = bid / 28;
        int rp = bid - bh * 28;
        int s  = 1;
        while ((s * (s + 1)) / 2 <= rp) ++s;
        int c  = rp - (s * (s - 1)) / 2;
        tile_work(p, skv, sq, spart, tid, bh, s, c);
    } else {
        // merged diagonal pair: tiles (2m,2m) and (2m+1,2m+1)
        int id2 = bid - NFULL;
        int bh  = id2 >> 2;
        int m   = id2 & 3;
        tile_work(p, skv, sq, spart, tid, bh, 2 * m,     2 * m);
        tile_work(p, skv, sq, spart, tid, bh, 2 * m + 1, 2 * m + 1);
    }
}

// ---------------------------------------------------------------------------
// Kernel 2: per-token epilogue (identical to the proven version).
// ---------------------------------------------------------------------------
__global__ __launch_bounds__(256) void epi_kernel(P p) {
    int gid = blockIdx.x * 256 + threadIdx.x;
    if (gid >= NTOK) return;
    int t = gid & (TT - 1);
    int b = gid >> 11;
    int s = t >> 8;

    float x[DM];
    int tok = p.idx[gid];
    #pragma unroll
    for (int j = 0; j < TOKD; ++j) x[j]        = p.tok_emb[tok * TOKD + j];
    #pragma unroll
    for (int j = 0; j < POSD; ++j) x[TOKD + j] = p.pos_enc[t * POSD + j];

    float att[AD];
    #pragma unroll
    for (int hh = 0; hh < NH; ++hh) {
        const float4* pp = p.pbuf + ((size_t)(b * NH + hh) * 8) * TT + t;
        float4 acc = pp[0];
        for (int c = 1; c <= s; ++c) {
            float4 e = pp[(size_t)c * TT];
            acc.x += e.x; acc.y += e.y; acc.z += e.z; acc.w += e.w;
        }
        float inv = 1.f / acc.w;
        att[hh*3+0] = acc.x * inv;
        att[hh*3+1] = acc.y * inv;
        att[hh*3+2] = acc.z * inv;
    }

    float xo[DM];
    #pragma unroll
    for (int j = 0; j < DM; ++j) {
        float sacc = x[j];
        #pragma unroll
        for (int a = 0; a < AD; ++a) sacc = fmaf(p.Wo[j * AD + a], att[a], sacc);
        xo[j] = sacc;
    }

    float m = 0.f;
    #pragma unroll
    for (int j = 0; j < DM; ++j) m += xo[j];
    m *= (1.f / DM);
    float v = 0.f;
    #pragma unroll
    for (int j = 0; j < DM; ++j) { float d = xo[j] - m; v += d * d; }
    v *= (1.f / DM);
    float rs = rsqrtf(v + 1e-5f);
    float h2[DM];
    #pragma unroll
    for (int j = 0; j < DM; ++j)
        h2[j] = (xo[j] - m) * rs * p.ln2w[j] + p.ln2b[j];

    float g[FFND];
    #pragma unroll
    for (int cc = 0; cc < FFND; ++cc) {
        float f = p.b1[cc];
        #pragma unroll
        for (int j = 0; j < DM; ++j) f = fmaf(p.W1[cc * DM + j], h2[j], f);
        g[cc] = 0.5f * f * (1.f + erff(f * 0.70710678118654752f));
    }
    float x2[DM];
    #pragma unroll
    for (int j = 0; j < DM; ++j) {
        float sacc = xo[j] + p.b2[j];
        #pragma unroll
        for (int cc = 0; cc < FFND; ++cc) sacc = fmaf(p.W2[j * FFND + cc], g[cc], sacc);
        x2[j] = sacc;
    }

    m = 0.f;
    #pragma unroll
    for (int j = 0; j < DM; ++j) m += x2[j];
    m *= (1.f / DM);
    v = 0.f;
    #pragma unroll
    for (int j = 0; j < DM; ++j) { float d = x2[j] - m; v += d * d; }
    v *= (1.f / DM);
    rs = rsqrtf(v + 1e-5f);
    float y[DM];
    #pragma unroll
    for (int j = 0; j < DM; ++j)
        y[j] = (x2[j] - m) * rs * p.lnfw[j] + p.lnfb[j];

    float t8[TOKD];
    #pragma unroll
    for (int pp = 0; pp < TOKD; ++pp) {
        float sacc = 0.f;
        #pragma unroll
        for (int j = 0; j < DM; ++j) sacc = fmaf(p.Wh[pp * DM + j], y[j], sacc);
        t8[pp] = sacc;
    }
    float* op = p.out + (size_t)gid * VOCAB;
    #pragma unroll
    for (int vcb = 0; vcb < VOCAB; ++vcb) {
        float sacc = 0.f;
        #pragma unroll
        for (int pp = 0; pp < TOKD; ++pp)
            sacc = fmaf(t8[pp], p.tok_emb[vcb * TOKD + pp], sacc);
        op[vcb] = sacc;
    }
}

// ---------------------------------------------------------------------------
extern "C" void kernel_launch(void* const* d_in, const int* in_sizes, int n_in,
                              void* d_out, int out_size, void* d_ws, size_t ws_size,
                              hipStream_t stream) {
    P p;
    p.idx     = (const int*)d_in[0];
    p.tok_emb = (const float*)d_in[1];
    p.pos_enc = (const float*)d_in[2];
    p.Wq      = (const float*)d_in[3];
    p.Wk      = (const float*)d_in[4];
    p.Wv      = (const float*)d_in[5];
    p.Wo      = (const float*)d_in[6];
    p.ln1w    = (const float*)d_in[7];
    p.ln1b    = (const float*)d_in[8];
    p.ln2w    = (const float*)d_in[9];
    p.ln2b    = (const float*)d_in[10];
    p.lnfw    = (const float*)d_in[11];
    p.lnfb    = (const float*)d_in[12];
    p.W1      = (const float*)d_in[13];
    p.b1      = (const float*)d_in[14];
    p.W2      = (const float*)d_in[15];
    p.b2      = (const float*)d_in[16];
    p.Wh      = (const float*)d_in[17];
    p.out     = (float*)d_out;
    p.pbuf    = (float4*)d_ws;                                  // 8 MB

    attn_kernel<<<NGRID, 256, 0, stream>>>(p);
    epi_kernel<<<NTOK / 256, 256, 0, stream>>>(p);
}

// Round 8
// 130.967 us; speedup vs baseline: 1.0323x; 1.0323x over previous
//
#include <hip/hip_runtime.h>
#include <math.h>

// Problem constants
#define BB    16
#define TT    2048
#define VOCAB 14
#define TOKD  8
#define POSD  8
#define DM    16      // TOKD + POSD
#define NH    2
#define HD    3
#define AD    6       // NH*HD
#define FFND  3

#define NTOK  (BB*TT)            // 32768
#define BH    (BB*NH)            // 32
#define TPB   36                 // tiles per bh: sum_{s=0..7}(s+1)
#define NTILE (BH*TPB)           // 1152 equal-cost tiles

struct P {
    const int*   idx;
    const float* tok_emb;
    const float* pos_enc;
    const float* Wq;
    const float* Wk;
    const float* Wv;
    const float* Wo;
    const float* ln1w;
    const float* ln1b;
    const float* ln2w;
    const float* ln2b;
    const float* lnfw;
    const float* lnfb;
    const float* W1;
    const float* b1;
    const float* W2;
    const float* b2;
    const float* Wh;
    float*       out;
    float4*      pbuf;   // [BH][8][TT] chunk partials {a0,a1,a2,l}, transposed
};

// LN1 output for token (b, t): embeddings gather + layernorm.
__device__ __forceinline__ void ln1_of(const P& p, int b, int t, float* h) {
    float x[DM];
    int tok = p.idx[b * TT + t];
    #pragma unroll
    for (int j = 0; j < TOKD; ++j) x[j]        = p.tok_emb[tok * TOKD + j];
    #pragma unroll
    for (int j = 0; j < POSD; ++j) x[TOKD + j] = p.pos_enc[t * POSD + j];

    float m = 0.f;
    #pragma unroll
    for (int j = 0; j < DM; ++j) m += x[j];
    m *= (1.f / DM);
    float v = 0.f;
    #pragma unroll
    for (int j = 0; j < DM; ++j) { float d = x[j] - m; v += d * d; }
    v *= (1.f / DM);
    float rs = rsqrtf(v + 1e-5f);
    #pragma unroll
    for (int j = 0; j < DM; ++j)
        h[j] = (x[j] - m) * rs * p.ln1w[j] + p.ln1b[j];
}

// Wave-uniform register broadcast of lane `it`'s value (VALU pipe, no LDS).
__device__ __forceinline__ float RL(float x, int it) {
    return __uint_as_float(__builtin_amdgcn_readlane(__float_as_uint(x), it));
}

// ---------------------------------------------------------------------------
// Kernel 1: attention tiles, REGISTER-RESIDENT K/V. Tile = (bh, 256-query
// super-row s, 256-key chunk c), c <= s; 1152 single-tile blocks (proven
// R6 grid). Lane l of wave wv preps key (c<<8)+(wv<<6)+l into 6 VGPRs
// (inline LN1+projection, this head only); the inner loop broadcasts each
// key with v_readlane (VALU pipe) — ZERO inner-loop LDS traffic and no
// lgkmcnt waits, breaking the 1:1 LDS:VALU pipe balance that stalled the
// LDS-staged version at 35% VALUBusy. Q is block-shared via LDS sq (read
// once per wave). Diagonal tiles: single loop, per-pair keyloc<=qloc mask.
// LDS = 20 KB -> 8 blocks/CU capacity.
// ---------------------------------------------------------------------------
__global__ __launch_bounds__(256) void attn_kernel(P p) {
    __shared__ float4 sq[256];       // 4 KB   prescaled q
    __shared__ float4 spart[1024];   // 16 KB  per-wave partials

    const int tid  = threadIdx.x;
    int tile = blockIdx.x;
    int bh   = tile / TPB;
    int r    = tile - bh * TPB;
    int s    = 0;
    while (((s + 1) * (s + 2)) / 2 <= r) ++s;
    int c    = r - (s * (s + 1)) / 2;
    int b    = bh >> 1;              // NH = 2
    int hh   = bh & 1;

    int wv   = tid >> 6;
    int lane = tid & 63;

    // --- inline prep: this thread's key -> registers, query -> LDS sq
    float rk0, rk1, rk2, rv0, rv1, rv2;
    {
        float hK[DM];
        ln1_of(p, b, (c << 8) + tid, hK);   // key token (c<<8)+(wv<<6)+lane
        float k0=0.f,k1=0.f,k2=0.f,v0=0.f,v1=0.f,v2=0.f;
        const float* wk  = p.Wk + (hh * 3) * 8;
        const float* wv_ = p.Wv + (hh * 3) * 8;
        #pragma unroll
        for (int j = 0; j < 8; ++j) {
            k0 = fmaf(wk[j],      hK[TOKD + j], k0);
            k1 = fmaf(wk[8 + j],  hK[TOKD + j], k1);
            k2 = fmaf(wk[16 + j], hK[TOKD + j], k2);
            v0 = fmaf(wv_[j],      hK[j], v0);
            v1 = fmaf(wv_[8 + j],  hK[j], v1);
            v2 = fmaf(wv_[16 + j], hK[j], v2);
        }
        rk0 = k0; rk1 = k1; rk2 = k2; rv0 = v0; rv1 = v1; rv2 = v2;

        float hQ[DM];
        if (c != s) {
            ln1_of(p, b, (s << 8) + tid, hQ);
        } else {
            #pragma unroll
            for (int j = 0; j < DM; ++j) hQ[j] = hK[j];   // same tokens
        }
        const float QS = 1.4426950408889634f / 1.7320508075688772f; // log2e/sqrt(HD)
        float q0=0.f,q1=0.f,q2=0.f;
        const float* wq = p.Wq + (hh * 3) * 8;
        #pragma unroll
        for (int j = 0; j < 8; ++j) {
            q0 = fmaf(wq[j],      hQ[TOKD + j], q0);
            q1 = fmaf(wq[8 + j],  hQ[TOKD + j], q1);
            q2 = fmaf(wq[16 + j], hQ[TOKD + j], q2);
        }
        sq[tid] = make_float4(q0 * QS, q1 * QS, q2 * QS, 0.f);
    }
    __syncthreads();

    float4 qr[4];
    #pragma unroll
    for (int j = 0; j < 4; ++j) qr[j] = sq[(j << 6) + lane];

    float ac[4][4];
    #pragma unroll
    for (int j = 0; j < 4; ++j)
        ac[j][0] = ac[j][1] = ac[j][2] = ac[j][3] = 0.f;

    if (c < s) {
        // fully unmasked: one readlane broadcast set serves all 4 query groups
        #pragma unroll 4
        for (int it = 0; it < 64; ++it) {
            float k0 = RL(rk0, it), k1 = RL(rk1, it), k2 = RL(rk2, it);
            float v0 = RL(rv0, it), v1 = RL(rv1, it), v2 = RL(rv2, it);
            #pragma unroll
            for (int j = 0; j < 4; ++j) {
                float sc = fmaf(qr[j].x, k0, fmaf(qr[j].y, k1, qr[j].z * k2));
                float pr = __builtin_amdgcn_exp2f(sc);
                ac[j][0] = fmaf(pr, v0, ac[j][0]);
                ac[j][1] = fmaf(pr, v1, ac[j][1]);
                ac[j][2] = fmaf(pr, v2, ac[j][2]);
                ac[j][3] += pr;
            }
        }
    } else {
        // diagonal tile: key (wv<<6)+it vs query (j<<6)+lane, single loop,
        // per-pair causal mask (groups j<wv produce all-zero contributions).
        int kwv = wv << 6;
        #pragma unroll 4
        for (int it = 0; it < 64; ++it) {
            float k0 = RL(rk0, it), k1 = RL(rk1, it), k2 = RL(rk2, it);
            float v0 = RL(rv0, it), v1 = RL(rv1, it), v2 = RL(rv2, it);
            int keyloc = kwv + it;
            #pragma unroll
            for (int j = 0; j < 4; ++j) {
                float sc = fmaf(qr[j].x, k0, fmaf(qr[j].y, k1, qr[j].z * k2));
                float pr = __builtin_amdgcn_exp2f(sc);
                pr = (keyloc <= ((j << 6) + lane)) ? pr : 0.f;
                ac[j][0] = fmaf(pr, v0, ac[j][0]);
                ac[j][1] = fmaf(pr, v1, ac[j][1]);
                ac[j][2] = fmaf(pr, v2, ac[j][2]);
                ac[j][3] += pr;
            }
        }
    }

    // per-wave partials (16B lane stride: 2-way, free)
    #pragma unroll
    for (int j = 0; j < 4; ++j)
        spart[(wv << 8) + (j << 6) + lane] =
            make_float4(ac[j][0], ac[j][1], ac[j][2], ac[j][3]);
    __syncthreads();

    // block reduce across 4 waves; coalesced transposed pbuf store
    float4 p0 = spart[tid];
    float4 p1 = spart[256 + tid];
    float4 p2 = spart[512 + tid];
    float4 p3 = spart[768 + tid];
    float4 acc = make_float4(p0.x+p1.x+p2.x+p3.x, p0.y+p1.y+p2.y+p3.y,
                             p0.z+p1.z+p2.z+p3.z, p0.w+p1.w+p2.w+p3.w);
    p.pbuf[((size_t)bh * 8 + c) * TT + (s << 8) + tid] = acc;
}

// ---------------------------------------------------------------------------
// Kernel 2: per-token epilogue (identical to the proven version).
// ---------------------------------------------------------------------------
__global__ __launch_bounds__(256) void epi_kernel(P p) {
    int gid = blockIdx.x * 256 + threadIdx.x;
    if (gid >= NTOK) return;
    int t = gid & (TT - 1);
    int b = gid >> 11;
    int s = t >> 8;

    float x[DM];
    int tok = p.idx[gid];
    #pragma unroll
    for (int j = 0; j < TOKD; ++j) x[j]        = p.tok_emb[tok * TOKD + j];
    #pragma unroll
    for (int j = 0; j < POSD; ++j) x[TOKD + j] = p.pos_enc[t * POSD + j];

    float att[AD];
    #pragma unroll
    for (int hh = 0; hh < NH; ++hh) {
        const float4* pp = p.pbuf + ((size_t)(b * NH + hh) * 8) * TT + t;
        float4 acc = pp[0];
        for (int c = 1; c <= s; ++c) {
            float4 e = pp[(size_t)c * TT];
            acc.x += e.x; acc.y += e.y; acc.z += e.z; acc.w += e.w;
        }
        float inv = 1.f / acc.w;
        att[hh*3+0] = acc.x * inv;
        att[hh*3+1] = acc.y * inv;
        att[hh*3+2] = acc.z * inv;
    }

    float xo[DM];
    #pragma unroll
    for (int j = 0; j < DM; ++j) {
        float sacc = x[j];
        #pragma unroll
        for (int a = 0; a < AD; ++a) sacc = fmaf(p.Wo[j * AD + a], att[a], sacc);
        xo[j] = sacc;
    }

    float m = 0.f;
    #pragma unroll
    for (int j = 0; j < DM; ++j) m += xo[j];
    m *= (1.f / DM);
    float v = 0.f;
    #pragma unroll
    for (int j = 0; j < DM; ++j) { float d = xo[j] - m; v += d * d; }
    v *= (1.f / DM);
    float rs = rsqrtf(v + 1e-5f);
    float h2[DM];
    #pragma unroll
    for (int j = 0; j < DM; ++j)
        h2[j] = (xo[j] - m) * rs * p.ln2w[j] + p.ln2b[j];

    float g[FFND];
    #pragma unroll
    for (int cc = 0; cc < FFND; ++cc) {
        float f = p.b1[cc];
        #pragma unroll
        for (int j = 0; j < DM; ++j) f = fmaf(p.W1[cc * DM + j], h2[j], f);
        g[cc] = 0.5f * f * (1.f + erff(f * 0.70710678118654752f));
    }
    float x2[DM];
    #pragma unroll
    for (int j = 0; j < DM; ++j) {
        float sacc = xo[j] + p.b2[j];
        #pragma unroll
        for (int cc = 0; cc < FFND; ++cc) sacc = fmaf(p.W2[j * FFND + cc], g[cc], sacc);
        x2[j] = sacc;
    }

    m = 0.f;
    #pragma unroll
    for (int j = 0; j < DM; ++j) m += x2[j];
    m *= (1.f / DM);
    v = 0.f;
    #pragma unroll
    for (int j = 0; j < DM; ++j) { float d = x2[j] - m; v += d * d; }
    v *= (1.f / DM);
    rs = rsqrtf(v + 1e-5f);
    float y[DM];
    #pragma unroll
    for (int j = 0; j < DM; ++j)
        y[j] = (x2[j] - m) * rs * p.lnfw[j] + p.lnfb[j];

    float t8[TOKD];
    #pragma unroll
    for (int pp = 0; pp < TOKD; ++pp) {
        float sacc = 0.f;
        #pragma unroll
        for (int j = 0; j < DM; ++j) sacc = fmaf(p.Wh[pp * DM + j], y[j], sacc);
        t8[pp] = sacc;
    }
    float* op = p.out + (size_t)gid * VOCAB;
    #pragma unroll
    for (int vcb = 0; vcb < VOCAB; ++vcb) {
        float sacc = 0.f;
        #pragma unroll
        for (int pp = 0; pp < TOKD; ++pp)
            sacc = fmaf(t8[pp], p.tok_emb[vcb * TOKD + pp], sacc);
        op[vcb] = sacc;
    }
}

// ---------------------------------------------------------------------------
extern "C" void kernel_launch(void* const* d_in, const int* in_sizes, int n_in,
                              void* d_out, int out_size, void* d_ws, size_t ws_size,
                              hipStream_t stream) {
    P p;
    p.idx     = (const int*)d_in[0];
    p.tok_emb = (const float*)d_in[1];
    p.pos_enc = (const float*)d_in[2];
    p.Wq      = (const float*)d_in[3];
    p.Wk      = (const float*)d_in[4];
    p.Wv      = (const float*)d_in[5];
    p.Wo      = (const float*)d_in[6];
    p.ln1w    = (const float*)d_in[7];
    p.ln1b    = (const float*)d_in[8];
    p.ln2w    = (const float*)d_in[9];
    p.ln2b    = (const float*)d_in[10];
    p.lnfw    = (const float*)d_in[11];
    p.lnfb    = (const float*)d_in[12];
    p.W1      = (const float*)d_in[13];
    p.b1      = (const float*)d_in[14];
    p.W2      = (const float*)d_in[15];
    p.b2      = (const float*)d_in[16];
    p.Wh      = (const float*)d_in[17];
    p.out     = (float*)d_out;
    p.pbuf    = (float4*)d_ws;                                  // 8 MB

    attn_kernel<<<NTILE, 256, 0, stream>>>(p);
    epi_kernel<<<NTOK / 256, 256, 0, stream>>>(p);
}

// Round 9
// 126.486 us; speedup vs baseline: 1.0688x; 1.0354x over previous
//
#include <hip/hip_runtime.h>
#include <math.h>

// Problem constants
#define BB    16
#define TT    2048
#define VOCAB 14
#define TOKD  8
#define POSD  8
#define DM    16      // TOKD + POSD
#define NH    2
#define HD    3
#define AD    6       // NH*HD
#define FFND  3

#define NTOK  (BB*TT)            // 32768
#define BH    (BB*NH)            // 32
#define TPB   36                 // tiles per bh: sum_{s=0..7}(s+1)
#define NTILE (BH*TPB)           // 1152 equal-cost tiles

struct P {
    const int*   idx;
    const float* tok_emb;
    const float* pos_enc;
    const float* Wq;
    const float* Wk;
    const float* Wv;
    const float* Wo;
    const float* ln1w;
    const float* ln1b;
    const float* ln2w;
    const float* ln2b;
    const float* lnfw;
    const float* lnfb;
    const float* W1;
    const float* b1;
    const float* W2;
    const float* b2;
    const float* Wh;
    float*       out;
    float4*      pbuf;   // [BH][8][TT] chunk partials {a0,a1,a2,l}, transposed
};

// LN1 output for token (b, t): embeddings gather + layernorm.
__device__ __forceinline__ void ln1_of(const P& p, int b, int t, float* h) {
    float x[DM];
    int tok = p.idx[b * TT + t];
    #pragma unroll
    for (int j = 0; j < TOKD; ++j) x[j]        = p.tok_emb[tok * TOKD + j];
    #pragma unroll
    for (int j = 0; j < POSD; ++j) x[TOKD + j] = p.pos_enc[t * POSD + j];

    float m = 0.f;
    #pragma unroll
    for (int j = 0; j < DM; ++j) m += x[j];
    m *= (1.f / DM);
    float v = 0.f;
    #pragma unroll
    for (int j = 0; j < DM; ++j) { float d = x[j] - m; v += d * d; }
    v *= (1.f / DM);
    float rs = rsqrtf(v + 1e-5f);
    #pragma unroll
    for (int j = 0; j < DM; ++j)
        h[j] = (x[j] - m) * rs * p.ln1w[j] + p.ln1b[j];
}

#define LOADKV(it)                                                             \
    float4 Kr = skv[((kw + (it)) << 1)];                                       \
    float4 Vr = skv[((kw + (it)) << 1) + 1];                                   \
    float k0 = Kr.x, k1 = Kr.y, k2 = Kr.z;                                     \
    float v0 = Vr.x, v1 = Vr.y, v2 = Vr.z;

// ---------------------------------------------------------------------------
// Kernel 1: attention tiles with INLINE PREP (the proven 127.1us structure).
// Changes vs that version, targeting the measured 35% VALU issue efficiency:
//   * __launch_bounds__(256, 5): VGPR budget 52 -> ~102 while keeping
//     5 blocks/CU (= LDS capacity; grid is 4.5/CU so still all-resident).
//     More registers -> deeper exp/ds_read scheduling by the compiler.
//   * #pragma unroll 8 on the unmasked inner loop: 8 keys x 4 groups of
//     independent exp->fma chains in flight to fill that budget.
// ---------------------------------------------------------------------------
__global__ __launch_bounds__(256, 5) void attn_kernel(P p) {
    __shared__ float4 skv[512];      // 8 KB
    __shared__ float4 sq[256];       // 4 KB
    __shared__ float4 spart[1024];   // 16 KB

    const int tid  = threadIdx.x;
    int tile = blockIdx.x;
    int bh   = tile / TPB;
    int r    = tile - bh * TPB;
    int s    = 0;
    while (((s + 1) * (s + 2)) / 2 <= r) ++s;
    int c    = r - (s * (s + 1)) / 2;
    int b    = bh >> 1;              // NH = 2
    int hh   = bh & 1;

    // --- inline prep: key-token for K/V, query-token for Q (this head only)
    {
        float hK[DM];
        ln1_of(p, b, (c << 8) + tid, hK);
        float k0=0.f,k1=0.f,k2=0.f,v0=0.f,v1=0.f,v2=0.f;
        const float* wk  = p.Wk + (hh * 3) * 8;
        const float* wv_ = p.Wv + (hh * 3) * 8;
        #pragma unroll
        for (int j = 0; j < 8; ++j) {
            k0 = fmaf(wk[j],      hK[TOKD + j], k0);
            k1 = fmaf(wk[8 + j],  hK[TOKD + j], k1);
            k2 = fmaf(wk[16 + j], hK[TOKD + j], k2);
            v0 = fmaf(wv_[j],      hK[j], v0);
            v1 = fmaf(wv_[8 + j],  hK[j], v1);
            v2 = fmaf(wv_[16 + j], hK[j], v2);
        }
        skv[(tid << 1)]     = make_float4(k0, k1, k2, 0.f);
        skv[(tid << 1) + 1] = make_float4(v0, v1, v2, 0.f);

        float hQ[DM];
        if (c != s) {
            ln1_of(p, b, (s << 8) + tid, hQ);
        } else {
            #pragma unroll
            for (int j = 0; j < DM; ++j) hQ[j] = hK[j];   // same tokens
        }
        const float QS = 1.4426950408889634f / 1.7320508075688772f; // log2e/sqrt(HD)
        float q0=0.f,q1=0.f,q2=0.f;
        const float* wq = p.Wq + (hh * 3) * 8;
        #pragma unroll
        for (int j = 0; j < 8; ++j) {
            q0 = fmaf(wq[j],      hQ[TOKD + j], q0);
            q1 = fmaf(wq[8 + j],  hQ[TOKD + j], q1);
            q2 = fmaf(wq[16 + j], hQ[TOKD + j], q2);
        }
        sq[tid] = make_float4(q0 * QS, q1 * QS, q2 * QS, 0.f);
    }
    __syncthreads();

    int wv   = tid >> 6;
    int lane = tid & 63;
    int kw   = wv << 6;

    float4 qr[4];
    #pragma unroll
    for (int j = 0; j < 4; ++j) qr[j] = sq[(j << 6) + lane];

    float ac[4][4];
    #pragma unroll
    for (int j = 0; j < 4; ++j)
        ac[j][0] = ac[j][1] = ac[j][2] = ac[j][3] = 0.f;

    if (c < s) {
        // fully unmasked: one K/V read serves all 4 query groups
        #pragma unroll 8
        for (int it = 0; it < 64; ++it) {
            LOADKV(it)
            #pragma unroll
            for (int j = 0; j < 4; ++j) {
                float sc = fmaf(qr[j].x, k0, fmaf(qr[j].y, k1, qr[j].z * k2));
                float pr = __builtin_amdgcn_exp2f(sc);
                ac[j][0] = fmaf(pr, v0, ac[j][0]);
                ac[j][1] = fmaf(pr, v1, ac[j][1]);
                ac[j][2] = fmaf(pr, v2, ac[j][2]);
                ac[j][3] += pr;
            }
        }
    } else {
        // diagonal tile: wave wv sees keys 64wv..64wv+63.
        // group j<wv fully masked (skip); j==wv triangular; j>wv unmasked.
        #pragma unroll
        for (int j = 0; j < 4; ++j) {
            if (j < wv) continue;              // wave-uniform skip
            if (j == wv) {
                #pragma unroll 4
                for (int it = 0; it < 64; ++it) {
                    LOADKV(it)
                    float sc = fmaf(qr[j].x, k0, fmaf(qr[j].y, k1, qr[j].z * k2));
                    float pr = __builtin_amdgcn_exp2f(sc);
                    pr = (it <= lane) ? pr : 0.f;
                    ac[j][0] = fmaf(pr, v0, ac[j][0]);
                    ac[j][1] = fmaf(pr, v1, ac[j][1]);
                    ac[j][2] = fmaf(pr, v2, ac[j][2]);
                    ac[j][3] += pr;
                }
            } else {
                #pragma unroll 4
                for (int it = 0; it < 64; ++it) {
                    LOADKV(it)
                    float sc = fmaf(qr[j].x, k0, fmaf(qr[j].y, k1, qr[j].z * k2));
                    float pr = __builtin_amdgcn_exp2f(sc);
                    ac[j][0] = fmaf(pr, v0, ac[j][0]);
                    ac[j][1] = fmaf(pr, v1, ac[j][1]);
                    ac[j][2] = fmaf(pr, v2, ac[j][2]);
                    ac[j][3] += pr;
                }
            }
        }
    }

    // per-wave partials (16B lane stride: 2-way, free)
    #pragma unroll
    for (int j = 0; j < 4; ++j)
        spart[(wv << 8) + (j << 6) + lane] =
            make_float4(ac[j][0], ac[j][1], ac[j][2], ac[j][3]);
    __syncthreads();

    // block reduce across 4 waves; coalesced transposed pbuf store
    float4 p0 = spart[tid];
    float4 p1 = spart[256 + tid];
    float4 p2 = spart[512 + tid];
    float4 p3 = spart[768 + tid];
    float4 acc = make_float4(p0.x+p1.x+p2.x+p3.x, p0.y+p1.y+p2.y+p3.y,
                             p0.z+p1.z+p2.z+p3.z, p0.w+p1.w+p2.w+p3.w);
    p.pbuf[((size_t)bh * 8 + c) * TT + (s << 8) + tid] = acc;
}

// ---------------------------------------------------------------------------
// Kernel 2: per-token epilogue (identical to the proven version).
// ---------------------------------------------------------------------------
__global__ __launch_bounds__(256) void epi_kernel(P p) {
    int gid = blockIdx.x * 256 + threadIdx.x;
    if (gid >= NTOK) return;
    int t = gid & (TT - 1);
    int b = gid >> 11;
    int s = t >> 8;

    float x[DM];
    int tok = p.idx[gid];
    #pragma unroll
    for (int j = 0; j < TOKD; ++j) x[j]        = p.tok_emb[tok * TOKD + j];
    #pragma unroll
    for (int j = 0; j < POSD; ++j) x[TOKD + j] = p.pos_enc[t * POSD + j];

    float att[AD];
    #pragma unroll
    for (int hh = 0; hh < NH; ++hh) {
        const float4* pp = p.pbuf + ((size_t)(b * NH + hh) * 8) * TT + t;
        float4 acc = pp[0];
        for (int c = 1; c <= s; ++c) {
            float4 e = pp[(size_t)c * TT];
            acc.x += e.x; acc.y += e.y; acc.z += e.z; acc.w += e.w;
        }
        float inv = 1.f / acc.w;
        att[hh*3+0] = acc.x * inv;
        att[hh*3+1] = acc.y * inv;
        att[hh*3+2] = acc.z * inv;
    }

    float xo[DM];
    #pragma unroll
    for (int j = 0; j < DM; ++j) {
        float sacc = x[j];
        #pragma unroll
        for (int a = 0; a < AD; ++a) sacc = fmaf(p.Wo[j * AD + a], att[a], sacc);
        xo[j] = sacc;
    }

    float m = 0.f;
    #pragma unroll
    for (int j = 0; j < DM; ++j) m += xo[j];
    m *= (1.f / DM);
    float v = 0.f;
    #pragma unroll
    for (int j = 0; j < DM; ++j) { float d = xo[j] - m; v += d * d; }
    v *= (1.f / DM);
    float rs = rsqrtf(v + 1e-5f);
    float h2[DM];
    #pragma unroll
    for (int j = 0; j < DM; ++j)
        h2[j] = (xo[j] - m) * rs * p.ln2w[j] + p.ln2b[j];

    float g[FFND];
    #pragma unroll
    for (int cc = 0; cc < FFND; ++cc) {
        float f = p.b1[cc];
        #pragma unroll
        for (int j = 0; j < DM; ++j) f = fmaf(p.W1[cc * DM + j], h2[j], f);
        g[cc] = 0.5f * f * (1.f + erff(f * 0.70710678118654752f));
    }
    float x2[DM];
    #pragma unroll
    for (int j = 0; j < DM; ++j) {
        float sacc = xo[j] + p.b2[j];
        #pragma unroll
        for (int cc = 0; cc < FFND; ++cc) sacc = fmaf(p.W2[j * FFND + cc], g[cc], sacc);
        x2[j] = sacc;
    }

    m = 0.f;
    #pragma unroll
    for (int j = 0; j < DM; ++j) m += x2[j];
    m *= (1.f / DM);
    v = 0.f;
    #pragma unroll
    for (int j = 0; j < DM; ++j) { float d = x2[j] - m; v += d * d; }
    v *= (1.f / DM);
    rs = rsqrtf(v + 1e-5f);
    float y[DM];
    #pragma unroll
    for (int j = 0; j < DM; ++j)
        y[j] = (x2[j] - m) * rs * p.lnfw[j] + p.lnfb[j];

    float t8[TOKD];
    #pragma unroll
    for (int pp = 0; pp < TOKD; ++pp) {
        float sacc = 0.f;
        #pragma unroll
        for (int j = 0; j < DM; ++j) sacc = fmaf(p.Wh[pp * DM + j], y[j], sacc);
        t8[pp] = sacc;
    }
    float* op = p.out + (size_t)gid * VOCAB;
    #pragma unroll
    for (int vcb = 0; vcb < VOCAB; ++vcb) {
        float sacc = 0.f;
        #pragma unroll
        for (int pp = 0; pp < TOKD; ++pp)
            sacc = fmaf(t8[pp], p.tok_emb[vcb * TOKD + pp], sacc);
        op[vcb] = sacc;
    }
}

// ---------------------------------------------------------------------------
extern "C" void kernel_launch(void* const* d_in, const int* in_sizes, int n_in,
                              void* d_out, int out_size, void* d_ws, size_t ws_size,
                              hipStream_t stream) {
    P p;
    p.idx     = (const int*)d_in[0];
    p.tok_emb = (const float*)d_in[1];
    p.pos_enc = (const float*)d_in[2];
    p.Wq      = (const float*)d_in[3];
    p.Wk      = (const float*)d_in[4];
    p.Wv      = (const float*)d_in[5];
    p.Wo      = (const float*)d_in[6];
    p.ln1w    = (const float*)d_in[7];
    p.ln1b    = (const float*)d_in[8];
    p.ln2w    = (const float*)d_in[9];
    p.ln2b    = (const float*)d_in[10];
    p.lnfw    = (const float*)d_in[11];
    p.lnfb    = (const float*)d_in[12];
    p.W1      = (const float*)d_in[13];
    p.b1      = (const float*)d_in[14];
    p.W2      = (const float*)d_in[15];
    p.b2      = (const float*)d_in[16];
    p.Wh      = (const float*)d_in[17];
    p.out     = (float*)d_out;
    p.pbuf    = (float4*)d_ws;                                  // 8 MB

    attn_kernel<<<NTILE, 256, 0, stream>>>(p);
    epi_kernel<<<NTOK / 256, 256, 0, stream>>>(p);
}